// Round 4
// baseline (515.265 us; speedup 1.0000x reference)
//
#include <hip/hip_runtime.h>

// FullyAdjacent rewiring: output is [2, G*N*N] int32, flattened.
//   rows half: out[j]        = (j % N^2) / N      (j in [0, half))
//   cols half: out[half + i] = i % N              (i in [0, half))
//
// Round 6: return to round-0's winning structure (dense one-shot grid, each
// store instruction = contiguous 1 KB wave write), with 2 stores/thread.
// Ledger (marginal kernel time = total - ~342us harness poison fill):
//   r0: 131K one-shot wgs, 1 store/thread           -> 161 us   (best)
//   r1: 2048 blocks, 64B/thread contiguous          -> 225 us   (per-instr scatter)
//   r2: 2048 blocks, 4 slots 8MB apart per thread   -> 190 us   (stream scatter)
//   r3: 256 blocks, sequential 2MB chunks           -> 172 us
// Revised model: ~75us of the marginal time is FIXED (poison fill's dirty
// L2/L3 writeback draining during our kernel + tiny restore dispatches), so
// r0 was already storing at ~6.2 TB/s = the fill's own ceiling. This version
// keeps r0's exact per-instruction pattern; each wave now covers a contiguous
// 2 KB region (two back-to-back 1 KB stores), halving workgroup count and
// amortizing the end-of-wave store drain. Plain cached stores (nontemporal
// measured 1.07 TB/s previously — keep L2).

typedef int v4i __attribute__((ext_vector_type(4)));

__global__ __launch_bounds__(256) void fa_pow2_kernel(
    int* __restrict__ out,
    unsigned n,         // total int32 elements
    unsigned half,      // n/2, multiple of 512
    int shiftN,         // log2(N)
    int maskN)          // N-1
{
    unsigned tid  = blockIdx.x * blockDim.x + threadIdx.x;
    unsigned lane = tid & 63u;
    // Each wave owns a contiguous 512-element (2 KB) region; two 1 KB stores.
    unsigned j0 = (tid >> 6) * 512u + lane * 4u;
    unsigned j1 = j0 + 256u;
    if (j1 >= n) {                       // partial-wave tail (not hit here)
        if (j0 < n) {
            int v0;
            if (j0 < half) v0 = (int)((j0 >> shiftN) & (unsigned)maskN);
            else           v0 = (int)((j0 - half) & (unsigned)maskN);
            v4i v = (j0 < half) ? (v4i){v0, v0, v0, v0}
                                : (v4i){v0, v0 + 1, v0 + 2, v0 + 3};
            *(v4i*)(out + j0) = v;
        }
        return;
    }
    if (j0 < half) {
        // rows: (j % N^2)/N == (j >> shiftN) & maskN for pow2 N.
        // Constant across each 4-group since 4 | N.
        int r0 = (int)((j0 >> shiftN) & (unsigned)maskN);
        int r1 = (int)((j1 >> shiftN) & (unsigned)maskN);
        *(v4i*)(out + j0) = (v4i){r0, r0, r0, r0};
        *(v4i*)(out + j1) = (v4i){r1, r1, r1, r1};
    } else {
        // cols: (j - half) % N; no wrap inside a 4-group since 4 | N and
        // all group bases are 4-aligned.
        int c0 = (int)((j0 - half) & (unsigned)maskN);
        int c1 = (int)((j1 - half) & (unsigned)maskN);
        *(v4i*)(out + j0) = (v4i){c0, c0 + 1, c0 + 2, c0 + 3};
        *(v4i*)(out + j1) = (v4i){c1, c1 + 1, c1 + 2, c1 + 3};
    }
}

// Fallback for non-pow2 N or unaligned sizes (not expected for this problem).
__global__ __launch_bounds__(256) void fa_generic_kernel(
    int* __restrict__ out, long long n, long long half, long long N)
{
    long long tid    = (long long)blockIdx.x * blockDim.x + threadIdx.x;
    long long stride = (long long)gridDim.x * blockDim.x;
    long long NN = N * N;
    for (long long j = tid; j < n; j += stride) {
        int val;
        if (j < half) val = (int)((j % NN) / N);
        else          val = (int)((j - half) % N);
        out[j] = val;
    }
}

extern "C" void kernel_launch(void* const* d_in, const int* in_sizes, int n_in,
                              void* d_out, int out_size, void* d_ws, size_t ws_size,
                              hipStream_t stream) {
    (void)d_in; (void)d_ws; (void)ws_size;
    int* out = (int*)d_out;
    long long n = (long long)out_size;     // total int32 elements
    long long half = n / 2;
    long long N = (n_in >= 3) ? (long long)in_sizes[2] : 4096;  // batch length

    bool pow2 = (N > 0) && ((N & (N - 1)) == 0);
    // Wave regions are 512-elem; need halves 512-aligned and 4 | N.
    bool aligned = (n % 2048 == 0) && (half % 512 == 0) && (N % 4 == 0);

    if (pow2 && aligned) {
        int shiftN = 0;
        while ((1LL << shiftN) < N) ++shiftN;
        int maskN = (int)(N - 1);
        // Each 256-thread wg covers 4 waves x 512 elems = 2048 elems.
        long long grid = n / 2048;
        fa_pow2_kernel<<<(dim3)(unsigned)grid, 256, 0, stream>>>(
            out, (unsigned)n, (unsigned)half, shiftN, maskN);
    } else {
        int block = 256;
        long long grid = (n + block - 1) / block;
        if (grid > 2048) grid = 2048;
        fa_generic_kernel<<<(dim3)(unsigned)grid, block, 0, stream>>>(
            out, n, half, N);
    }
}

// Round 5
// 501.079 us; speedup vs baseline: 1.0283x; 1.0283x over previous
//
#include <hip/hip_runtime.h>

// FullyAdjacent rewiring: output is [2, G*N*N] int32, flattened.
//   rows half: out[j]        = (j % N^2) / N      (j in [0, half))
//   cols half: out[half + i] = i % N              (i in [0, half))
// N = in_sizes[2] (batch length), half = out_size/2 (G baked in by harness).
// Pure store-bound kernel: one 16B vector (4 consecutive int32) per thread.
//
// FINAL (round 7): byte-identical revert to the round-0 source (501-503 us,
// reproduced across two sessions). Exploration ledger (total us):
//   r0: 131K one-shot wgs, 1 store/thread            -> 502.6  (this source)
//   r1: 2048 blocks, 64B/thread contiguous           -> 567.8
//   r2: 2048 blocks, 4 slots 8MB apart per thread    -> 532.4
//   r3: 256 blocks, sequential 2MB chunks            -> 514.8
//   r4: 65K one-shot wgs, 2 stores/thread            -> 515.3
// Every structural deviation lost. Model of the floor: harness poison fill
// (2.147 GB @ 6.3 TB/s = ~343us, untouchable) + ~75us fixed tax (fill's dirty
// L2/L3 writeback draining during our window + tiny restore dispatches) +
// 537 MB output @ ~6.3 TB/s (~85us) = ~503us. The kernel-side store stream is
// at the measured achievable HBM write ceiling.
// Nontemporal stores measured 1.07 TB/s (bypasses L2 write coalescing): keep
// plain cached stores. 32-bit indexing (out_size is an int).

typedef int v4i __attribute__((ext_vector_type(4)));

__global__ __launch_bounds__(256) void fa_pow2_kernel(
    int* __restrict__ out,
    unsigned n,         // total int32 elements (fits: out_size is int)
    unsigned half,      // n/2, multiple of 4
    int shiftN,         // log2(N)
    int maskN)          // N-1
{
    unsigned i4 = blockIdx.x * blockDim.x + threadIdx.x;
    unsigned j = i4 << 2;               // int32 index of this lane's group
    if (j >= n) return;
    v4i v;
    if (j < half) {
        // rows: (j % N^2)/N == (j >> shiftN) & maskN for pow2 N.
        // Constant across the 4-group since 4 | N.
        int r = (int)((j >> shiftN) & (unsigned)maskN);
        v = (v4i){r, r, r, r};
    } else {
        // cols: (j - half) % N; no wrap inside the 4-group since 4 | N.
        int c = (int)((j - half) & (unsigned)maskN);
        v = (v4i){c, c + 1, c + 2, c + 3};
    }
    *(v4i*)(out + j) = v;   // plain global_store_dwordx4, L2-cached
}

// Fallback for non-pow2 N or unaligned sizes (not expected for this problem).
__global__ __launch_bounds__(256) void fa_generic_kernel(
    int* __restrict__ out, long long n, long long half, long long N)
{
    long long j = (long long)blockIdx.x * blockDim.x + threadIdx.x;
    if (j >= n) return;
    long long NN = N * N;
    int val;
    if (j < half) val = (int)((j % NN) / N);
    else          val = (int)((j - half) % N);
    out[j] = val;
}

extern "C" void kernel_launch(void* const* d_in, const int* in_sizes, int n_in,
                              void* d_out, int out_size, void* d_ws, size_t ws_size,
                              hipStream_t stream) {
    (void)d_in; (void)d_ws; (void)ws_size;
    int* out = (int*)d_out;
    long long n = (long long)out_size;
    long long half = n / 2;
    long long N = (n_in >= 3) ? (long long)in_sizes[2] : 4096;  // batch length

    bool pow2 = (N > 0) && ((N & (N - 1)) == 0);
    bool aligned = (n % 4 == 0) && (half % 4 == 0) && (N % 4 == 0);

    if (pow2 && aligned) {
        int shiftN = 0;
        while ((1LL << shiftN) < N) ++shiftN;
        int maskN = (int)(N - 1);
        long long n4 = n >> 2;
        int block = 256;
        long long grid = (n4 + block - 1) / block;
        fa_pow2_kernel<<<(dim3)(unsigned)grid, block, 0, stream>>>(
            out, (unsigned)n, (unsigned)half, shiftN, maskN);
    } else {
        int block = 256;
        long long grid = (n + block - 1) / block;
        fa_generic_kernel<<<(dim3)(unsigned)grid, block, 0, stream>>>(
            out, n, half, N);
    }
}